// Round 2
// baseline (365.584 us; speedup 1.0000x reference)
//
#include <hip/hip_runtime.h>
#include <hip/hip_bf16.h>

// out[e] = concat(node_states[src[e]], node_states[tgt[e]])
// One wave (64 lanes) per edge: row = 256 fp32 = 64 float4 -> one float4/lane.
// Lanes 0-31 cover the source half, lanes 32-63 the target half.
// Nontemporal stores keep the 328 MB output stream out of L2 so the 5 MB
// node_states table stays cached for the gather reads.

typedef float v4f __attribute__((ext_vector_type(4)));  // native vector: OK for
                                                        // __builtin_nontemporal_store

__global__ __launch_bounds__(256) void NodePropagator_75110388073048_kernel(
    const v4f* __restrict__ ns,       // node_states as [N, 32] v4f
    const int* __restrict__ src32,    // edge_sources (int32 view)
    const int* __restrict__ tgt32,    // edge_targets (int32 view)
    v4f* __restrict__ out,            // [E, 64] v4f
    int nEdges)
{
    int tid  = blockIdx.x * blockDim.x + threadIdx.x;
    int e    = tid >> 6;              // edge index
    if (e >= nEdges) return;
    int lane = tid & 63;
    int half = lane >> 5;             // 0 = source half, 1 = target half
    int c    = lane & 31;             // v4f chunk within the half

    // --- index dtype probe (int64 vs int32), wave-uniform, cached loads ---
    // Reference casts indices to int64 (values < 10000 -> high words all 0);
    // harness doc claims int32. If int64, every odd int32 word is 0.
    // For genuine int32 data, 4 random values in [0,10000) all being 0 has
    // probability ~1e-16.
    bool is_i64 = (src32[1] == 0) & (src32[3] == 0) &
                  (src32[5] == 0) & (src32[7] == 0);

    const int* idxp = half ? tgt32 : src32;
    int row;
    if (is_i64) {
        row = (int)((const long long*)idxp)[e];
    } else {
        row = idxp[e];
    }

    v4f v = ns[row * 32 + c];
    __builtin_nontemporal_store(v, &out[e * 64 + lane]);
}

extern "C" void kernel_launch(void* const* d_in, const int* in_sizes, int n_in,
                              void* d_out, int out_size, void* d_ws, size_t ws_size,
                              hipStream_t stream) {
    const v4f* ns  = (const v4f*)d_in[0];
    const int* src = (const int*)d_in[1];
    const int* tgt = (const int*)d_in[2];
    v4f*       out = (v4f*)d_out;

    int nEdges = in_sizes[1];                 // 320000
    long long totalThreads = (long long)nEdges * 64;   // one v4f per thread
    int block = 256;
    int grid  = (int)((totalThreads + block - 1) / block);

    NodePropagator_75110388073048_kernel<<<grid, block, 0, stream>>>(
        ns, src, tgt, out, nEdges);
}